// Round 1
// baseline (11.350 us; speedup 1.0000x reference)
//
#include <hip/hip_runtime.h>
#include <hip/hip_bf16.h>

#define N_QUBITS 20
#define BATCH 4

// Closed-form evaluation of the 20-qubit circuit:
//   pre-CNOT product state => per-qubit z_j = cos(w1_j) * cos(x_j + w0_j)
//   ring CNOTs = basis permutation with prefix-XOR bits =>
//     Z_k = prod_{j=0..k} z_j (k>=1),  Z_0 = prod_{j=1..19} z_j
//   then logits = Z @ fc_w^T + fc_b, log_softmax.
__global__ void QNN_1975684956466_kernel(const float* __restrict__ x,      // (B, n)
                                         const float* __restrict__ w,      // (n, 3)
                                         const float* __restrict__ fw,     // (3, n)
                                         const float* __restrict__ fb,     // (3,)
                                         float* __restrict__ out) {        // (B, 3)
    int b = threadIdx.x;
    if (b >= BATCH) return;

    float z[N_QUBITS];
    #pragma unroll
    for (int j = 0; j < N_QUBITS; ++j) {
        float w0 = w[j * 3 + 0];
        float w1 = w[j * 3 + 1];
        z[j] = cosf(w1) * cosf(x[b * N_QUBITS + j] + w0);
    }

    float zo[N_QUBITS];
    float p = z[0];
    #pragma unroll
    for (int k = 1; k < N_QUBITS; ++k) { p *= z[k]; zo[k] = p; }
    float p0 = 1.0f;
    #pragma unroll
    for (int j = 1; j < N_QUBITS; ++j) p0 *= z[j];
    zo[0] = p0;

    float logits[3];
    #pragma unroll
    for (int m = 0; m < 3; ++m) {
        float acc = fb[m];
        #pragma unroll
        for (int k = 0; k < N_QUBITS; ++k) acc += zo[k] * fw[m * N_QUBITS + k];
        logits[m] = acc;
    }

    float mx = fmaxf(logits[0], fmaxf(logits[1], logits[2]));
    float se = __expf(logits[0] - mx) + __expf(logits[1] - mx) + __expf(logits[2] - mx);
    float ls = mx + logf(se);
    #pragma unroll
    for (int m = 0; m < 3; ++m) out[b * 3 + m] = logits[m] - ls;
}

extern "C" void kernel_launch(void* const* d_in, const int* in_sizes, int n_in,
                              void* d_out, int out_size, void* d_ws, size_t ws_size,
                              hipStream_t stream) {
    const float* x  = (const float*)d_in[0];   // (4, 20)
    const float* w  = (const float*)d_in[1];   // (20, 3)
    const float* fw = (const float*)d_in[2];   // (3, 20)
    const float* fb = (const float*)d_in[3];   // (3,)
    float* out = (float*)d_out;                // (4, 3)
    QNN_1975684956466_kernel<<<1, 64, 0, stream>>>(x, w, fw, fb, out);
}